// Round 2
// baseline (505.129 us; speedup 1.0000x reference)
//
#include <hip/hip_runtime.h>

#define NN 50000
#define NE 640000
#define SCAN_T 1024

// ---- detect whether edge_index arrived as int64 or int32 ----
// int64 non-negative values < 2^31 have all-zero high words at odd 32-bit
// positions. Sample 256 odd words within the first NE*2 words (safe for both
// layouts). flag=1 -> int64, flag=0 -> int32.
__global__ void k_detect(const unsigned* __restrict__ w, int* __restrict__ flag) {
    __shared__ int found;
    if (threadIdx.x == 0) found = 0;
    __syncthreads();
    int j = threadIdx.x * 2499;          // j < 640000
    if (w[2 * j + 1] != 0u) atomicAdd(&found, 1);
    __syncthreads();
    if (threadIdx.x == 0) *flag = (found == 0) ? 1 : 0;
}

__device__ __forceinline__ int edge_at(const void* p, long long i, int m64) {
    if (m64) return (int)((const long long*)p)[i];
    return ((const int*)p)[i];
}

// ---- count in-degree (col side, excluding self-loops) ----
__global__ void k_count(const void* __restrict__ e, const int* __restrict__ flag,
                        int* __restrict__ deg) {
    int i = blockIdx.x * 256 + threadIdx.x;
    if (i >= NE) return;
    int m = *flag;
    int c = edge_at(e, (long long)NE + i, m);
    if ((unsigned)c < (unsigned)NN) atomicAdd(&deg[c], 1);
}

// ---- single-block exclusive scan over deg; also emits cursor copy and dinv ----
__global__ __launch_bounds__(SCAN_T) void k_scan(const int* __restrict__ deg,
                                                 int* __restrict__ offs,
                                                 int* __restrict__ cursor,
                                                 float* __restrict__ dinv) {
    __shared__ int part[SCAN_T];
    int t = threadIdx.x;
    const int chunk = (NN + SCAN_T - 1) / SCAN_T;   // 49
    int lo = t * chunk;
    int hi = lo + chunk; if (hi > NN) hi = NN;
    int s = 0;
    for (int i = lo; i < hi; i++) s += deg[i];
    part[t] = s;
    __syncthreads();
    for (int d = 1; d < SCAN_T; d <<= 1) {
        int v = (t >= d) ? part[t - d] : 0;
        __syncthreads();
        part[t] += v;
        __syncthreads();
    }
    int run = (t == 0) ? 0 : part[t - 1];
    for (int i = lo; i < hi; i++) {
        offs[i] = run;
        cursor[i] = run;
        int dg = deg[i];
        run += dg;
        dinv[i] = rsqrtf((float)(dg + 1));   // +1 self-loop
    }
    if (t == SCAN_T - 1) offs[NN] = run;
}

// ---- scatter edges into CSR buckets; precompute per-edge weight dinv[row] ----
__global__ void k_scatter(const void* __restrict__ e, const int* __restrict__ flag,
                          int* __restrict__ cursor, int* __restrict__ srcs,
                          float* __restrict__ wts, const float* __restrict__ dinv) {
    int i = blockIdx.x * 256 + threadIdx.x;
    if (i >= NE) return;
    int m = *flag;
    int c = edge_at(e, (long long)NE + i, m);
    if ((unsigned)c >= (unsigned)NN) return;
    int r = edge_at(e, (long long)i, m);
    r = min(max(r, 0), NN - 1);
    int p = atomicAdd(&cursor[c], 1);
    srcs[p] = r;
    wts[p] = dinv[r];
}

// ---- GEMM: T[N,128] = A[N,128] @ W[128,128]; W staged in LDS ----
__global__ __launch_bounds__(256) void k_gemm128(const float* __restrict__ A,
                                                 const float* __restrict__ W,
                                                 float* __restrict__ T) {
    __shared__ float Ws[128 * 128];
    int t = threadIdx.x;
#pragma unroll
    for (int i = 0; i < 16; i++)
        ((float4*)Ws)[t + 256 * i] = ((const float4*)W)[t + 256 * i];
    __syncthreads();
    int rg = t >> 4, cg = t & 15;
    int row0 = blockIdx.x * 64 + rg * 4;
    const float* a0 = A + (long long)min(row0 + 0, NN - 1) * 128;
    const float* a1 = A + (long long)min(row0 + 1, NN - 1) * 128;
    const float* a2 = A + (long long)min(row0 + 2, NN - 1) * 128;
    const float* a3 = A + (long long)min(row0 + 3, NN - 1) * 128;
    float acc[4][8];
#pragma unroll
    for (int i = 0; i < 4; i++)
#pragma unroll
        for (int j = 0; j < 8; j++) acc[i][j] = 0.f;
#pragma unroll 8
    for (int k = 0; k < 128; k++) {
        float4 w0 = *(const float4*)&Ws[k * 128 + cg * 4];
        float4 w1 = *(const float4*)&Ws[k * 128 + cg * 4 + 64];
        float a[4] = {a0[k], a1[k], a2[k], a3[k]};
#pragma unroll
        for (int i = 0; i < 4; i++) {
            acc[i][0] += a[i] * w0.x; acc[i][1] += a[i] * w0.y;
            acc[i][2] += a[i] * w0.z; acc[i][3] += a[i] * w0.w;
            acc[i][4] += a[i] * w1.x; acc[i][5] += a[i] * w1.y;
            acc[i][6] += a[i] * w1.z; acc[i][7] += a[i] * w1.w;
        }
    }
#pragma unroll
    for (int i = 0; i < 4; i++) {
        int row = row0 + i;
        if (row < NN) {
            float4 v0 = {acc[i][0], acc[i][1], acc[i][2], acc[i][3]};
            float4 v1 = {acc[i][4], acc[i][5], acc[i][6], acc[i][7]};
            *(float4*)&T[(long long)row * 128 + cg * 4] = v0;
            *(float4*)&T[(long long)row * 128 + cg * 4 + 64] = v1;
        }
    }
}

// ---- final GEMM with bias: out[N,64] = A[N,128] @ W[128,64] + b ----
__global__ __launch_bounds__(256) void k_gemm64(const float* __restrict__ A,
                                                const float* __restrict__ W,
                                                const float* __restrict__ b,
                                                float* __restrict__ T) {
    __shared__ float Ws[128 * 64];
    int t = threadIdx.x;
#pragma unroll
    for (int i = 0; i < 8; i++)
        ((float4*)Ws)[t + 256 * i] = ((const float4*)W)[t + 256 * i];
    __syncthreads();
    int rg = t >> 4, cg = t & 15;
    int row0 = blockIdx.x * 64 + rg * 4;
    const float* a0 = A + (long long)min(row0 + 0, NN - 1) * 128;
    const float* a1 = A + (long long)min(row0 + 1, NN - 1) * 128;
    const float* a2 = A + (long long)min(row0 + 2, NN - 1) * 128;
    const float* a3 = A + (long long)min(row0 + 3, NN - 1) * 128;
    float acc[4][4];
#pragma unroll
    for (int i = 0; i < 4; i++)
#pragma unroll
        for (int j = 0; j < 4; j++) acc[i][j] = 0.f;
#pragma unroll 8
    for (int k = 0; k < 128; k++) {
        float4 w = *(const float4*)&Ws[k * 64 + cg * 4];
        float a[4] = {a0[k], a1[k], a2[k], a3[k]};
#pragma unroll
        for (int i = 0; i < 4; i++) {
            acc[i][0] += a[i] * w.x; acc[i][1] += a[i] * w.y;
            acc[i][2] += a[i] * w.z; acc[i][3] += a[i] * w.w;
        }
    }
    float4 bb = ((const float4*)b)[cg];
#pragma unroll
    for (int i = 0; i < 4; i++) {
        int row = row0 + i;
        if (row < NN) {
            float4 v = {acc[i][0] + bb.x, acc[i][1] + bb.y,
                        acc[i][2] + bb.z, acc[i][3] + bb.w};
            *(float4*)&T[(long long)row * 64 + cg * 4] = v;
        }
    }
}

// ---- aggregation: H[c] = relu(dinv[c]*(sum_e wts[e]*X[src] + dinv[c]*X[c]) + b)
// one wave (64 lanes) per node, float2 per lane -> one 512B row per load instr,
// no intra-wave divergence (edge loop uniform within wave).
__global__ __launch_bounds__(256) void k_agg(const float* __restrict__ X,
                                             const int* __restrict__ offs,
                                             const int* __restrict__ srcs,
                                             const float* __restrict__ wts,
                                             const float* __restrict__ dinv,
                                             const float* __restrict__ b,
                                             float* __restrict__ H) {
    int t = threadIdx.x;
    int node = blockIdx.x * 4 + (t >> 6);
    int h = t & 63;
    if (node >= NN) return;
    const float2* X2 = (const float2*)X;
    float dc = dinv[node];
    float2 self = X2[(long long)node * 64 + h];
    float2 acc;
    acc.x = dc * self.x;
    acc.y = dc * self.y;
    int e0 = offs[node], e1 = offs[node + 1];
    for (int e = e0; e < e1; e++) {
        int r = srcs[e];
        float w = wts[e];
        float2 v = X2[(long long)r * 64 + h];
        acc.x += w * v.x;
        acc.y += w * v.y;
    }
    float2 bb = ((const float2*)b)[h];
    float2 o;
    o.x = fmaxf(dc * acc.x + bb.x, 0.f);
    o.y = fmaxf(dc * acc.y + bb.y, 0.f);
    *(float2*)&H[(long long)node * 128 + 2 * h] = o;
}

extern "C" void kernel_launch(void* const* d_in, const int* in_sizes, int n_in,
                              void* d_out, int out_size, void* d_ws, size_t ws_size,
                              hipStream_t stream) {
    const float* x  = (const float*)d_in[0];
    const void*  ei = d_in[1];
    const float* W1 = (const float*)d_in[2];
    const float* b1 = (const float*)d_in[3];
    const float* W2 = (const float*)d_in[4];
    const float* b2 = (const float*)d_in[5];
    const float* Wl = (const float*)d_in[6];
    const float* bl = (const float*)d_in[7];
    float* out = (float*)d_out;

    char* ws = (char*)d_ws;
    size_t off = 0;
    auto alloc = [&](size_t bytes) {
        void* p = ws + off;
        off += (bytes + 255) & ~(size_t)255;
        return p;
    };
    float* t0     = (float*)alloc((size_t)NN * 128 * 4);
    float* t1     = (float*)alloc((size_t)NN * 128 * 4);
    int*   deg    = (int*)alloc((size_t)NN * 4);
    int*   offs   = (int*)alloc((size_t)(NN + 1) * 4);
    int*   cursor = (int*)alloc((size_t)NN * 4);
    int*   srcs   = (int*)alloc((size_t)NE * 4);
    float* wts    = (float*)alloc((size_t)NE * 4);
    float* dinv   = (float*)alloc((size_t)NN * 4);
    int*   flag   = (int*)alloc(256);

    hipMemsetAsync(deg, 0, (size_t)NN * 4, stream);
    k_detect<<<1, 256, 0, stream>>>((const unsigned*)ei, flag);
    k_count<<<(NE + 255) / 256, 256, 0, stream>>>(ei, flag, deg);
    k_scan<<<1, SCAN_T, 0, stream>>>(deg, offs, cursor, dinv);
    k_scatter<<<(NE + 255) / 256, 256, 0, stream>>>(ei, flag, cursor, srcs, wts, dinv);

    int gb = (NN + 63) / 64;
    k_gemm128<<<gb, 256, 0, stream>>>(x, W1, t0);
    k_agg<<<(NN + 3) / 4, 256, 0, stream>>>(t0, offs, srcs, wts, dinv, b1, t1);
    k_gemm128<<<gb, 256, 0, stream>>>(t1, W2, t0);
    k_agg<<<(NN + 3) / 4, 256, 0, stream>>>(t0, offs, srcs, wts, dinv, b2, t1);
    k_gemm64<<<gb, 256, 0, stream>>>(t1, Wl, bl, out);
}

// Round 3
// 355.045 us; speedup vs baseline: 1.4227x; 1.4227x over previous
//
#include <hip/hip_runtime.h>

#define NN 50000
#define NE 640000
#define RB ((NN + 255) / 256)   // 196 scan blocks

// ---- detect whether edge_index arrived as int64 or int32 ----
__global__ void k_detect(const unsigned* __restrict__ w, int* __restrict__ flag) {
    __shared__ int found;
    if (threadIdx.x == 0) found = 0;
    __syncthreads();
    int j = threadIdx.x * 2499;          // j < 640000
    if (w[2 * j + 1] != 0u) atomicAdd(&found, 1);
    __syncthreads();
    if (threadIdx.x == 0) *flag = (found == 0) ? 1 : 0;
}

__device__ __forceinline__ int edge_at(const void* p, long long i, int m64) {
    if (m64) return (int)((const long long*)p)[i];
    return ((const int*)p)[i];
}

// ---- count in-degree (col side, excluding self-loops) ----
__global__ void k_count(const void* __restrict__ e, const int* __restrict__ flag,
                        int* __restrict__ deg) {
    int i = blockIdx.x * 256 + threadIdx.x;
    if (i >= NE) return;
    int m = *flag;
    int c = edge_at(e, (long long)NE + i, m);
    if ((unsigned)c < (unsigned)NN) atomicAdd(&deg[c], 1);
}

// ---- two-level scan: per-block reduce -> tiny scan -> per-block apply ----
__global__ __launch_bounds__(256) void k_reduce(const int* __restrict__ deg,
                                                int* __restrict__ bsum) {
    __shared__ int s[256];
    int i = blockIdx.x * 256 + threadIdx.x;
    s[threadIdx.x] = (i < NN) ? deg[i] : 0;
    __syncthreads();
    for (int d = 128; d > 0; d >>= 1) {
        if (threadIdx.x < d) s[threadIdx.x] += s[threadIdx.x + d];
        __syncthreads();
    }
    if (threadIdx.x == 0) bsum[blockIdx.x] = s[0];
}

__global__ __launch_bounds__(256) void k_scanb(const int* __restrict__ bsum,
                                               int* __restrict__ bpref) {
    __shared__ int s[256];
    int t = threadIdx.x;
    s[t] = (t < RB) ? bsum[t] : 0;
    __syncthreads();
    for (int d = 1; d < 256; d <<= 1) {
        int v = (t >= d) ? s[t - d] : 0;
        __syncthreads();
        s[t] += v;
        __syncthreads();
    }
    if (t < RB) bpref[t] = (t == 0) ? 0 : s[t - 1];
}

__global__ __launch_bounds__(256) void k_apply(const int* __restrict__ deg,
                                               const int* __restrict__ bpref,
                                               int* __restrict__ offs,
                                               int* __restrict__ cursor,
                                               float* __restrict__ dinv) {
    __shared__ int s[256];
    int t = threadIdx.x;
    int i = blockIdx.x * 256 + t;
    int dg = (i < NN) ? deg[i] : 0;
    s[t] = dg;
    __syncthreads();
    for (int d = 1; d < 256; d <<= 1) {
        int v = (t >= d) ? s[t - d] : 0;
        __syncthreads();
        s[t] += v;
        __syncthreads();
    }
    if (i < NN) {
        int excl = bpref[blockIdx.x] + s[t] - dg;
        offs[i] = excl;
        cursor[i] = excl;
        dinv[i] = rsqrtf((float)(dg + 1));   // +1 self-loop
        if (i == NN - 1) offs[NN] = excl + dg;
    }
}

// ---- scatter edges into CSR buckets; precompute per-edge weight dinv[row] ----
__global__ void k_scatter(const void* __restrict__ e, const int* __restrict__ flag,
                          int* __restrict__ cursor, int* __restrict__ srcs,
                          float* __restrict__ wts, const float* __restrict__ dinv) {
    int i = blockIdx.x * 256 + threadIdx.x;
    if (i >= NE) return;
    int m = *flag;
    int c = edge_at(e, (long long)NE + i, m);
    if ((unsigned)c >= (unsigned)NN) return;
    int r = edge_at(e, (long long)i, m);
    r = min(max(r, 0), NN - 1);
    int p = atomicAdd(&cursor[c], 1);
    srcs[p] = r;
    wts[p] = dinv[r];
}

// ---- GEMM: T[N,128] = A[N,128] @ W[128,128]; W staged in LDS ----
__global__ __launch_bounds__(256) void k_gemm128(const float* __restrict__ A,
                                                 const float* __restrict__ W,
                                                 float* __restrict__ T) {
    __shared__ float Ws[128 * 128];
    int t = threadIdx.x;
#pragma unroll
    for (int i = 0; i < 16; i++)
        ((float4*)Ws)[t + 256 * i] = ((const float4*)W)[t + 256 * i];
    __syncthreads();
    int rg = t >> 4, cg = t & 15;
    int row0 = blockIdx.x * 64 + rg * 4;
    const float* a0 = A + (long long)min(row0 + 0, NN - 1) * 128;
    const float* a1 = A + (long long)min(row0 + 1, NN - 1) * 128;
    const float* a2 = A + (long long)min(row0 + 2, NN - 1) * 128;
    const float* a3 = A + (long long)min(row0 + 3, NN - 1) * 128;
    float acc[4][8];
#pragma unroll
    for (int i = 0; i < 4; i++)
#pragma unroll
        for (int j = 0; j < 8; j++) acc[i][j] = 0.f;
#pragma unroll 8
    for (int k = 0; k < 128; k++) {
        float4 w0 = *(const float4*)&Ws[k * 128 + cg * 4];
        float4 w1 = *(const float4*)&Ws[k * 128 + cg * 4 + 64];
        float a[4] = {a0[k], a1[k], a2[k], a3[k]};
#pragma unroll
        for (int i = 0; i < 4; i++) {
            acc[i][0] += a[i] * w0.x; acc[i][1] += a[i] * w0.y;
            acc[i][2] += a[i] * w0.z; acc[i][3] += a[i] * w0.w;
            acc[i][4] += a[i] * w1.x; acc[i][5] += a[i] * w1.y;
            acc[i][6] += a[i] * w1.z; acc[i][7] += a[i] * w1.w;
        }
    }
#pragma unroll
    for (int i = 0; i < 4; i++) {
        int row = row0 + i;
        if (row < NN) {
            float4 v0 = {acc[i][0], acc[i][1], acc[i][2], acc[i][3]};
            float4 v1 = {acc[i][4], acc[i][5], acc[i][6], acc[i][7]};
            *(float4*)&T[(long long)row * 128 + cg * 4] = v0;
            *(float4*)&T[(long long)row * 128 + cg * 4 + 64] = v1;
        }
    }
}

// ---- final GEMM with bias: out[N,64] = A[N,128] @ W[128,64] + b ----
__global__ __launch_bounds__(256) void k_gemm64(const float* __restrict__ A,
                                                const float* __restrict__ W,
                                                const float* __restrict__ b,
                                                float* __restrict__ T) {
    __shared__ float Ws[128 * 64];
    int t = threadIdx.x;
#pragma unroll
    for (int i = 0; i < 8; i++)
        ((float4*)Ws)[t + 256 * i] = ((const float4*)W)[t + 256 * i];
    __syncthreads();
    int rg = t >> 4, cg = t & 15;
    int row0 = blockIdx.x * 64 + rg * 4;
    const float* a0 = A + (long long)min(row0 + 0, NN - 1) * 128;
    const float* a1 = A + (long long)min(row0 + 1, NN - 1) * 128;
    const float* a2 = A + (long long)min(row0 + 2, NN - 1) * 128;
    const float* a3 = A + (long long)min(row0 + 3, NN - 1) * 128;
    float acc[4][4];
#pragma unroll
    for (int i = 0; i < 4; i++)
#pragma unroll
        for (int j = 0; j < 4; j++) acc[i][j] = 0.f;
#pragma unroll 8
    for (int k = 0; k < 128; k++) {
        float4 w = *(const float4*)&Ws[k * 64 + cg * 4];
        float a[4] = {a0[k], a1[k], a2[k], a3[k]};
#pragma unroll
        for (int i = 0; i < 4; i++) {
            acc[i][0] += a[i] * w.x; acc[i][1] += a[i] * w.y;
            acc[i][2] += a[i] * w.z; acc[i][3] += a[i] * w.w;
        }
    }
    float4 bb = ((const float4*)b)[cg];
#pragma unroll
    for (int i = 0; i < 4; i++) {
        int row = row0 + i;
        if (row < NN) {
            float4 v = {acc[i][0] + bb.x, acc[i][1] + bb.y,
                        acc[i][2] + bb.z, acc[i][3] + bb.w};
            *(float4*)&T[(long long)row * 64 + cg * 4] = v;
        }
    }
}

// ---- aggregation: H[c] = relu(dinv[c]*(sum_e wts[e]*X[src] + dinv[c]*X[c]) + b)
// one wave per node; edge loop unrolled x2 for two independent gathers in flight.
__global__ __launch_bounds__(256) void k_agg(const float* __restrict__ X,
                                             const int* __restrict__ offs,
                                             const int* __restrict__ srcs,
                                             const float* __restrict__ wts,
                                             const float* __restrict__ dinv,
                                             const float* __restrict__ b,
                                             float* __restrict__ H) {
    int t = threadIdx.x;
    int node = blockIdx.x * 4 + (t >> 6);
    int h = t & 63;
    if (node >= NN) return;
    const float2* X2 = (const float2*)X;
    float dc = dinv[node];
    float2 self = X2[(long long)node * 64 + h];
    float accx = dc * self.x, accy = dc * self.y;
    int e0 = offs[node], e1 = offs[node + 1];
    int e = e0;
    for (; e + 1 < e1; e += 2) {
        int r0 = srcs[e], r1 = srcs[e + 1];
        float w0 = wts[e], w1 = wts[e + 1];
        float2 v0 = X2[(long long)r0 * 64 + h];
        float2 v1 = X2[(long long)r1 * 64 + h];
        accx += w0 * v0.x + w1 * v1.x;
        accy += w0 * v0.y + w1 * v1.y;
    }
    if (e < e1) {
        int r = srcs[e];
        float w = wts[e];
        float2 v = X2[(long long)r * 64 + h];
        accx += w * v.x;
        accy += w * v.y;
    }
    float2 bb = ((const float2*)b)[h];
    float2 o;
    o.x = fmaxf(dc * accx + bb.x, 0.f);
    o.y = fmaxf(dc * accy + bb.y, 0.f);
    *(float2*)&H[(long long)node * 128 + 2 * h] = o;
}

extern "C" void kernel_launch(void* const* d_in, const int* in_sizes, int n_in,
                              void* d_out, int out_size, void* d_ws, size_t ws_size,
                              hipStream_t stream) {
    const float* x  = (const float*)d_in[0];
    const void*  ei = d_in[1];
    const float* W1 = (const float*)d_in[2];
    const float* b1 = (const float*)d_in[3];
    const float* W2 = (const float*)d_in[4];
    const float* b2 = (const float*)d_in[5];
    const float* Wl = (const float*)d_in[6];
    const float* bl = (const float*)d_in[7];
    float* out = (float*)d_out;

    char* ws = (char*)d_ws;
    size_t off = 0;
    auto alloc = [&](size_t bytes) {
        void* p = ws + off;
        off += (bytes + 255) & ~(size_t)255;
        return p;
    };
    float* t0     = (float*)alloc((size_t)NN * 128 * 4);
    float* t1     = (float*)alloc((size_t)NN * 128 * 4);
    int*   deg    = (int*)alloc((size_t)NN * 4);
    int*   offs   = (int*)alloc((size_t)(NN + 1) * 4);
    int*   cursor = (int*)alloc((size_t)NN * 4);
    int*   srcs   = (int*)alloc((size_t)NE * 4);
    float* wts    = (float*)alloc((size_t)NE * 4);
    float* dinv   = (float*)alloc((size_t)NN * 4);
    int*   bsum   = (int*)alloc((size_t)RB * 4);
    int*   bpref  = (int*)alloc((size_t)RB * 4);
    int*   flag   = (int*)alloc(256);

    hipMemsetAsync(deg, 0, (size_t)NN * 4, stream);
    k_detect<<<1, 256, 0, stream>>>((const unsigned*)ei, flag);
    k_count<<<(NE + 255) / 256, 256, 0, stream>>>(ei, flag, deg);
    k_reduce<<<RB, 256, 0, stream>>>(deg, bsum);
    k_scanb<<<1, 256, 0, stream>>>(bsum, bpref);
    k_apply<<<RB, 256, 0, stream>>>(deg, bpref, offs, cursor, dinv);
    k_scatter<<<(NE + 255) / 256, 256, 0, stream>>>(ei, flag, cursor, srcs, wts, dinv);

    int gb = (NN + 63) / 64;
    k_gemm128<<<gb, 256, 0, stream>>>(x, W1, t0);
    k_agg<<<(NN + 3) / 4, 256, 0, stream>>>(t0, offs, srcs, wts, dinv, b1, t1);
    k_gemm128<<<gb, 256, 0, stream>>>(t1, W2, t0);
    k_agg<<<(NN + 3) / 4, 256, 0, stream>>>(t0, offs, srcs, wts, dinv, b2, t1);
    k_gemm64<<<gb, 256, 0, stream>>>(t1, Wl, bl, out);
}

// Round 5
// 333.806 us; speedup vs baseline: 1.5132x; 1.0636x over previous
//
#include <hip/hip_runtime.h>

#define NN 50000
#define NE 640000
#define RB ((NN + 255) / 256)   // 196 scan blocks

struct __align__(8) edge_t { int r; float w; };

// ---- detect whether edge_index arrived as int64 or int32 ----
__global__ void k_detect(const unsigned* __restrict__ w, int* __restrict__ flag) {
    __shared__ int found;
    if (threadIdx.x == 0) found = 0;
    __syncthreads();
    int j = threadIdx.x * 2499;          // j < 640000
    if (w[2 * j + 1] != 0u) atomicAdd(&found, 1);
    __syncthreads();
    if (threadIdx.x == 0) *flag = (found == 0) ? 1 : 0;
}

__device__ __forceinline__ int edge_at(const void* p, long long i, int m64) {
    if (m64) return (int)((const long long*)p)[i];
    return ((const int*)p)[i];
}

// ---- count in-degree (col side, excluding self-loops) ----
__global__ void k_count(const void* __restrict__ e, const int* __restrict__ flag,
                        int* __restrict__ deg) {
    int i = blockIdx.x * 256 + threadIdx.x;
    if (i >= NE) return;
    int m = *flag;
    int c = edge_at(e, (long long)NE + i, m);
    if ((unsigned)c < (unsigned)NN) atomicAdd(&deg[c], 1);
}

// ---- two-level scan: per-block reduce -> tiny scan -> per-block apply ----
__global__ __launch_bounds__(256) void k_reduce(const int* __restrict__ deg,
                                                int* __restrict__ bsum) {
    __shared__ int s[256];
    int i = blockIdx.x * 256 + threadIdx.x;
    s[threadIdx.x] = (i < NN) ? deg[i] : 0;
    __syncthreads();
    for (int d = 128; d > 0; d >>= 1) {
        if (threadIdx.x < d) s[threadIdx.x] += s[threadIdx.x + d];
        __syncthreads();
    }
    if (threadIdx.x == 0) bsum[blockIdx.x] = s[0];
}

__global__ __launch_bounds__(256) void k_scanb(const int* __restrict__ bsum,
                                               int* __restrict__ bpref) {
    __shared__ int s[256];
    int t = threadIdx.x;
    s[t] = (t < RB) ? bsum[t] : 0;
    __syncthreads();
    for (int d = 1; d < 256; d <<= 1) {
        int v = (t >= d) ? s[t - d] : 0;
        __syncthreads();
        s[t] += v;
        __syncthreads();
    }
    if (t < RB) bpref[t] = (t == 0) ? 0 : s[t - 1];
}

__global__ __launch_bounds__(256) void k_apply(const int* __restrict__ deg,
                                               const int* __restrict__ bpref,
                                               int* __restrict__ offs,
                                               int* __restrict__ cursor,
                                               float* __restrict__ dinv) {
    __shared__ int s[256];
    int t = threadIdx.x;
    int i = blockIdx.x * 256 + t;
    int dg = (i < NN) ? deg[i] : 0;
    s[t] = dg;
    __syncthreads();
    for (int d = 1; d < 256; d <<= 1) {
        int v = (t >= d) ? s[t - d] : 0;
        __syncthreads();
        s[t] += v;
        __syncthreads();
    }
    if (i < NN) {
        int excl = bpref[blockIdx.x] + s[t] - dg;
        offs[i] = excl;
        cursor[i] = excl;
        dinv[i] = rsqrtf((float)(dg + 1));   // +1 self-loop
        if (i == NN - 1) offs[NN] = excl + dg;
    }
}

// ---- scatter edges into CSR buckets; per-edge (src, dinv[src]) packed 8B ----
__global__ void k_scatter(const void* __restrict__ e, const int* __restrict__ flag,
                          int* __restrict__ cursor, edge_t* __restrict__ ew,
                          const float* __restrict__ dinv) {
    int i = blockIdx.x * 256 + threadIdx.x;
    if (i >= NE) return;
    int m = *flag;
    int c = edge_at(e, (long long)NE + i, m);
    if ((unsigned)c >= (unsigned)NN) return;
    int r = edge_at(e, (long long)i, m);
    r = min(max(r, 0), NN - 1);
    int p = atomicAdd(&cursor[c], 1);
    edge_t t2; t2.r = r; t2.w = dinv[r];
    ew[p] = t2;
}

// ---- GEMM: T[N,128] = A[N,128] @ W[128,128]; W staged in LDS ----
__global__ __launch_bounds__(256) void k_gemm128(const float* __restrict__ A,
                                                 const float* __restrict__ W,
                                                 float* __restrict__ T) {
    __shared__ float Ws[128 * 128];
    int t = threadIdx.x;
#pragma unroll
    for (int i = 0; i < 16; i++)
        ((float4*)Ws)[t + 256 * i] = ((const float4*)W)[t + 256 * i];
    __syncthreads();
    int rg = t >> 4, cg = t & 15;
    int row0 = blockIdx.x * 64 + rg * 4;
    const float* a0 = A + (long long)min(row0 + 0, NN - 1) * 128;
    const float* a1 = A + (long long)min(row0 + 1, NN - 1) * 128;
    const float* a2 = A + (long long)min(row0 + 2, NN - 1) * 128;
    const float* a3 = A + (long long)min(row0 + 3, NN - 1) * 128;
    float acc[4][8];
#pragma unroll
    for (int i = 0; i < 4; i++)
#pragma unroll
        for (int j = 0; j < 8; j++) acc[i][j] = 0.f;
#pragma unroll 8
    for (int k = 0; k < 128; k++) {
        float4 w0 = *(const float4*)&Ws[k * 128 + cg * 4];
        float4 w1 = *(const float4*)&Ws[k * 128 + cg * 4 + 64];
        float a[4] = {a0[k], a1[k], a2[k], a3[k]};
#pragma unroll
        for (int i = 0; i < 4; i++) {
            acc[i][0] += a[i] * w0.x; acc[i][1] += a[i] * w0.y;
            acc[i][2] += a[i] * w0.z; acc[i][3] += a[i] * w0.w;
            acc[i][4] += a[i] * w1.x; acc[i][5] += a[i] * w1.y;
            acc[i][6] += a[i] * w1.z; acc[i][7] += a[i] * w1.w;
        }
    }
#pragma unroll
    for (int i = 0; i < 4; i++) {
        int row = row0 + i;
        if (row < NN) {
            float4 v0 = {acc[i][0], acc[i][1], acc[i][2], acc[i][3]};
            float4 v1 = {acc[i][4], acc[i][5], acc[i][6], acc[i][7]};
            *(float4*)&T[(long long)row * 128 + cg * 4] = v0;
            *(float4*)&T[(long long)row * 128 + cg * 4 + 64] = v1;
        }
    }
}

// ---- final GEMM with bias: out[N,64] = A[N,128] @ W[128,64] + b ----
__global__ __launch_bounds__(256) void k_gemm64(const float* __restrict__ A,
                                                const float* __restrict__ W,
                                                const float* __restrict__ b,
                                                float* __restrict__ T) {
    __shared__ float Ws[128 * 64];
    int t = threadIdx.x;
#pragma unroll
    for (int i = 0; i < 8; i++)
        ((float4*)Ws)[t + 256 * i] = ((const float4*)W)[t + 256 * i];
    __syncthreads();
    int rg = t >> 4, cg = t & 15;
    int row0 = blockIdx.x * 64 + rg * 4;
    const float* a0 = A + (long long)min(row0 + 0, NN - 1) * 128;
    const float* a1 = A + (long long)min(row0 + 1, NN - 1) * 128;
    const float* a2 = A + (long long)min(row0 + 2, NN - 1) * 128;
    const float* a3 = A + (long long)min(row0 + 3, NN - 1) * 128;
    float acc[4][4];
#pragma unroll
    for (int i = 0; i < 4; i++)
#pragma unroll
        for (int j = 0; j < 4; j++) acc[i][j] = 0.f;
#pragma unroll 8
    for (int k = 0; k < 128; k++) {
        float4 w = *(const float4*)&Ws[k * 64 + cg * 4];
        float a[4] = {a0[k], a1[k], a2[k], a3[k]};
#pragma unroll
        for (int i = 0; i < 4; i++) {
            acc[i][0] += a[i] * w.x; acc[i][1] += a[i] * w.y;
            acc[i][2] += a[i] * w.z; acc[i][3] += a[i] * w.w;
        }
    }
    float4 bb = ((const float4*)b)[cg];
#pragma unroll
    for (int i = 0; i < 4; i++) {
        int row = row0 + i;
        if (row < NN) {
            float4 v = {acc[i][0] + bb.x, acc[i][1] + bb.y,
                        acc[i][2] + bb.z, acc[i][3] + bb.w};
            *(float4*)&T[(long long)row * 64 + cg * 4] = v;
        }
    }
}

// ---- aggregation: H[c] = relu(dinv[c]*(sum_e w_e*X[src_e] + dinv[c]*X[c]) + b)
// one wave per node; 8/4/1 software pipeline -> up to 8 row-gathers in flight.
__global__ __launch_bounds__(256) void k_agg(const float* __restrict__ X,
                                             const int* __restrict__ offs,
                                             const edge_t* __restrict__ ew,
                                             const float* __restrict__ dinv,
                                             const float* __restrict__ b,
                                             float* __restrict__ H) {
    int t = threadIdx.x;
    int node = blockIdx.x * 4 + (t >> 6);
    int h = t & 63;
    if (node >= NN) return;
    const float2* X2 = (const float2*)X;
    float dc = dinv[node];
    float2 self = X2[(long long)node * 64 + h];
    float accx = dc * self.x, accy = dc * self.y;
    int e0 = offs[node], e1 = offs[node + 1];
    const edge_t* ep = ew + e0;
    int n = e1 - e0;
    int i = 0;
    for (; i + 8 <= n; i += 8) {
        edge_t m0 = ep[i+0], m1 = ep[i+1], m2 = ep[i+2], m3 = ep[i+3];
        edge_t m4 = ep[i+4], m5 = ep[i+5], m6 = ep[i+6], m7 = ep[i+7];
        float2 v0 = X2[(long long)m0.r * 64 + h];
        float2 v1 = X2[(long long)m1.r * 64 + h];
        float2 v2 = X2[(long long)m2.r * 64 + h];
        float2 v3 = X2[(long long)m3.r * 64 + h];
        float2 v4 = X2[(long long)m4.r * 64 + h];
        float2 v5 = X2[(long long)m5.r * 64 + h];
        float2 v6 = X2[(long long)m6.r * 64 + h];
        float2 v7 = X2[(long long)m7.r * 64 + h];
        accx += m0.w * v0.x + m1.w * v1.x + m2.w * v2.x + m3.w * v3.x
              + m4.w * v4.x + m5.w * v5.x + m6.w * v6.x + m7.w * v7.x;
        accy += m0.w * v0.y + m1.w * v1.y + m2.w * v2.y + m3.w * v3.y
              + m4.w * v4.y + m5.w * v5.y + m6.w * v6.y + m7.w * v7.y;
    }
    for (; i + 4 <= n; i += 4) {
        edge_t m0 = ep[i+0], m1 = ep[i+1], m2 = ep[i+2], m3 = ep[i+3];
        float2 v0 = X2[(long long)m0.r * 64 + h];
        float2 v1 = X2[(long long)m1.r * 64 + h];
        float2 v2 = X2[(long long)m2.r * 64 + h];
        float2 v3 = X2[(long long)m3.r * 64 + h];
        accx += m0.w * v0.x + m1.w * v1.x + m2.w * v2.x + m3.w * v3.x;
        accy += m0.w * v0.y + m1.w * v1.y + m2.w * v2.y + m3.w * v3.y;
    }
    for (; i < n; i++) {
        edge_t m = ep[i];
        float2 v = X2[(long long)m.r * 64 + h];
        accx += m.w * v.x;
        accy += m.w * v.y;
    }
    float2 bb = ((const float2*)b)[h];
    float2 o;
    o.x = fmaxf(dc * accx + bb.x, 0.f);
    o.y = fmaxf(dc * accy + bb.y, 0.f);
    *(float2*)&H[(long long)node * 128 + 2 * h] = o;
}

extern "C" void kernel_launch(void* const* d_in, const int* in_sizes, int n_in,
                              void* d_out, int out_size, void* d_ws, size_t ws_size,
                              hipStream_t stream) {
    const float* x  = (const float*)d_in[0];
    const void*  ei = d_in[1];
    const float* W1 = (const float*)d_in[2];
    const float* b1 = (const float*)d_in[3];
    const float* W2 = (const float*)d_in[4];
    const float* b2 = (const float*)d_in[5];
    const float* Wl = (const float*)d_in[6];
    const float* bl = (const float*)d_in[7];
    float* out = (float*)d_out;

    char* ws = (char*)d_ws;
    size_t off = 0;
    auto alloc = [&](size_t bytes) {
        void* p = ws + off;
        off += (bytes + 255) & ~(size_t)255;
        return p;
    };
    float*  t0     = (float*)alloc((size_t)NN * 128 * 4);
    float*  t1     = (float*)alloc((size_t)NN * 128 * 4);
    int*    deg    = (int*)alloc((size_t)NN * 4);
    int*    offs   = (int*)alloc((size_t)(NN + 1) * 4);
    int*    cursor = (int*)alloc((size_t)NN * 4);
    edge_t* ewbuf  = (edge_t*)alloc((size_t)NE * 8);
    float*  dinv   = (float*)alloc((size_t)NN * 4);
    int*    bsum   = (int*)alloc((size_t)RB * 4);
    int*    bpref  = (int*)alloc((size_t)RB * 4);
    int*    flag   = (int*)alloc(256);

    hipMemsetAsync(deg, 0, (size_t)NN * 4, stream);
    k_detect<<<1, 256, 0, stream>>>((const unsigned*)ei, flag);
    k_count<<<(NE + 255) / 256, 256, 0, stream>>>(ei, flag, deg);
    k_reduce<<<RB, 256, 0, stream>>>(deg, bsum);
    k_scanb<<<1, 256, 0, stream>>>(bsum, bpref);
    k_apply<<<RB, 256, 0, stream>>>(deg, bpref, offs, cursor, dinv);
    k_scatter<<<(NE + 255) / 256, 256, 0, stream>>>(ei, flag, cursor, ewbuf, dinv);

    int gb = (NN + 63) / 64;
    k_gemm128<<<gb, 256, 0, stream>>>(x, W1, t0);
    k_agg<<<(NN + 3) / 4, 256, 0, stream>>>(t0, offs, ewbuf, dinv, b1, t1);
    k_gemm128<<<gb, 256, 0, stream>>>(t1, W2, t0);
    k_agg<<<(NN + 3) / 4, 256, 0, stream>>>(t0, offs, ewbuf, dinv, b2, t1);
    k_gemm64<<<gb, 256, 0, stream>>>(t1, Wl, bl, out);
}